// Round 2
// baseline (90.600 us; speedup 1.0000x reference)
//
#include <hip/hip_runtime.h>
#include <math.h>

#ifndef M_PI
#define M_PI 3.14159265358979323846
#endif

typedef _Float16 half8v __attribute__((ext_vector_type(8)));
typedef float float4v __attribute__((ext_vector_type(4)));

constexpr int KDIM = 128;
constexpr int LTOT = 8192;
constexpr int TILE_L = 64;
constexpr int NT = 256;
constexpr int WSTR = 136;   // LDS row stride in halves (128 + 8 pad)

// ---------------------------------------------------------------------------
// V3: V1-exact structure (4 waves, mi-split GEMM, 2-half build) with wyT
// ELIMINATED from LDS. wy values are generated in-register in the reduce:
// each lane needs wy[l=16ni+ln][p=32w+16mi+4qd+reg]; seed sincos(posy/2),
// rotate to p0=32w+4qd by exact constants (qd*pi/32 per-lane, w*pi/4
// wave-uniform), then beta-rotations (V1's validated recurrence + slow path).
// LDS 38.9KB -> 21.3KB: 4 -> 7 blocks/CU (16 -> 28 waves/CU).
//   wx     : Dirichlet weights via rotation recurrence (V1 program, tid<128)
//   tmp    = psi * WX via mfma_f32_16x16x32_f16 (V1 loop, acc[2][4])
//   C_b    = sum (-1)^{p+q} psi from the GEMM's own A loads (V1)
//   out[l] = (sum_p wy[p][l]*tmp[p][l] - sin64x*sin64y*C_b) / K^2
// RULE (R4-R7 isolation): never hold A-fragment registers live across the
// unrolled build loop — a_raw is loaded strictly after it.
// ---------------------------------------------------------------------------
__global__ __launch_bounds__(NT, 7) void main_kernel(const float* __restrict__ x0,
        const float* __restrict__ y0, const float* __restrict__ psi,
        float* __restrict__ out) {
    __shared__ _Float16 wxT[TILE_L][WSTR];         // [l][q]
    __shared__ float ndh[KDIM], ndl[KDIM], ndh2[KDIM], ndl2[KDIM];
    __shared__ float s64X[TILE_L];
    __shared__ float posyL[TILE_L];
    __shared__ float s64Y[TILE_L];
    __shared__ float partial[4][TILE_L];
    __shared__ float cbred[4];

    const int tid = threadIdx.x;
    const int lane = tid & 63;
    const int w = tid >> 6;
    const int bid = blockIdx.x;
    const int b = bid >> 7;
    const int l0 = (bid & 127) * TILE_L;
    const int qd = lane >> 4;          // quad 0..3
    const int ln = lane & 15;

    const float* Pb = psi + (size_t)b * 16384;

    // ---- node tables for the rare slow path ----
    if (tid < KDIM) {
        double d = (double)tid * (M_PI / 64.0);
        float h = (float)d;
        ndh[tid] = h; ndl[tid] = (float)(d - (double)h);
        double d2 = d - 2.0 * M_PI;
        float h2 = (float)d2;
        ndh2[tid] = h2; ndl2[tid] = (float)(d2 - (double)h2);
    }

    // ---- setup: tid<128 are wx builders (V1 program: l=tid&63, hf=tid>>6);
    //      tid in [128,192) stage y-tile (posy, sin(64 y)) for the reduce ----
    const int l = tid & 63;
    const int hf = (tid >> 6) & 1;
    float pos = 0.f, s64 = 0.f, cs_s = 0.f, cs_c = 0.f;
    if (tid < 128) {
        pos = x0[(size_t)b * LTOT + l0 + l];
        s64 = sinf(64.0f * pos);
        float sa, ca;
        sincosf(0.5f * pos, &sa, &ca);
        if (hf == 0) { cs_s = sa; cs_c = ca; s64X[l] = s64; }
        else         { cs_s = -ca; cs_c = sa; }        // exact rotate by -pi/2
    } else if (tid < 192) {
        const int i = tid - 128;
        float py = y0[(size_t)b * LTOT + l0 + i];
        posyL[i] = py;
        s64Y[i] = sinf(64.0f * py);
    }
    __syncthreads();

    // ---- build wx: w(t_q) = (-1)^q sin(64 pos) cos(th)/sin(th), th = pos/2 - q*beta
    const float CB  = 0.9996988186962042f,  SB  = 0.024541228522912288f;  // beta = pi/128
    const float C16 = 0.9238795325112867f,  S16 = 0.3826834323650898f;    // 16*beta
    const float step = (float)(M_PI / 64.0);
    if (tid < 128) {
        _Float16* dst = &wxT[l][0];
#pragma unroll
        for (int kk = 0; kk < 4; ++kk) {
            float ws_ = cs_s, wc_ = cs_c;
            const int q0 = 64 * hf + 16 * kk;
#pragma unroll
            for (int h8 = 0; h8 < 2; ++h8) {
                _Float16 buf[8];
#pragma unroll
                for (int j = 0; j < 8; ++j) {
                    const int q = q0 + 8 * h8 + j;
                    const float num = (j & 1) ? -s64 : s64;   // sin(64 t_q) exactly
                    float wv;
                    if (__builtin_expect(fabsf(ws_) >= 2e-3f, 1)) {
                        wv = num * wc_ * __builtin_amdgcn_rcpf(ws_);
                    } else {
                        // near grid node: rebuild u = t_q in two-float, Taylor ratio
                        float ta = pos - step * (float)q;
                        float nh, nl;
                        if (ta > -1.0f) { nh = ndh[q];  nl = ndl[q]; }
                        else            { nh = ndh2[q]; nl = ndl2[q]; }
                        float u = (pos - nh) - nl;
                        if (fabsf(u) < 1e-7f) {
                            wv = 128.0f;
                        } else {
                            float hh = 0.5f * u;
                            float s2 = hh * (1.0f - 0.16666667f * hh * hh);
                            float c2 = 1.0f - 0.5f * hh * hh;
                            wv = num * c2 * __builtin_amdgcn_rcpf(s2);
                        }
                    }
                    buf[j] = (_Float16)wv;
                    float ns = ws_ * CB - wc_ * SB;    // rotate by -beta
                    wc_ = wc_ * CB + ws_ * SB;
                    ws_ = ns;
                }
                *(half8v*)&dst[q0 + 8 * h8] = *(half8v*)buf;
            }
            float ns = cs_s * C16 - cs_c * S16;        // reseed: rotate by -16*beta
            cs_c = cs_c * C16 + cs_s * S16;
            cs_s = ns;
        }
    }
    __syncthreads();

    // ---- A k0 load (fp32, L2/HBM), strictly AFTER the build (V1) ----
    float4v a_raw[2][2];
#pragma unroll
    for (int mi = 0; mi < 2; ++mi) {
        const float* rp = Pb + (32 * w + 16 * mi + ln) * 128 + 8 * qd;
        a_raw[mi][0] = *(const float4v*)(rp);
        a_raw[mi][1] = *(const float4v*)(rp + 4);
    }

    // ---- GEMM + in-flight C_b from the same A values (V1) ----
    float4v acc[2][4];
#pragma unroll
    for (int mi = 0; mi < 2; ++mi)
#pragma unroll
        for (int ni = 0; ni < 4; ++ni) acc[mi][ni] = (float4v){0.f, 0.f, 0.f, 0.f};

    float cbs = 0.0f;
#pragma unroll
    for (int k = 0; k < 4; ++k) {
        half8v af[2];
#pragma unroll
        for (int mi = 0; mi < 2; ++mi) {
#pragma unroll
            for (int j = 0; j < 4; ++j) {
                af[mi][j]     = (_Float16)a_raw[mi][0][j];
                af[mi][4 + j] = (_Float16)a_raw[mi][1][j];
            }
            cbs += (a_raw[mi][0].x - a_raw[mi][0].y) + (a_raw[mi][0].z - a_raw[mi][0].w)
                 + (a_raw[mi][1].x - a_raw[mi][1].y) + (a_raw[mi][1].z - a_raw[mi][1].w);
        }
        if (k < 3) {   // prefetch next k-step (af/cbs already captured the values)
#pragma unroll
            for (int mi = 0; mi < 2; ++mi) {
                const float* rp = Pb + (32 * w + 16 * mi + ln) * 128 + (k + 1) * 32 + 8 * qd;
                a_raw[mi][0] = *(const float4v*)(rp);
                a_raw[mi][1] = *(const float4v*)(rp + 4);
            }
        }
#pragma unroll
        for (int ni = 0; ni < 4; ++ni) {
            half8v bf = *(const half8v*)&wxT[16 * ni + ln][k * 32 + 8 * qd];
#pragma unroll
            for (int mi = 0; mi < 2; ++mi)
                acc[mi][ni] = __builtin_amdgcn_mfma_f32_16x16x32_f16(af[mi], bf, acc[mi][ni], 0, 0, 0);
        }
    }

    // row-parity sign, deterministic wave reduction, one partial per wave (V1)
    if (ln & 1) cbs = -cbs;
#pragma unroll
    for (int off = 1; off < 64; off <<= 1) cbs += __shfl_xor(cbs, off, 64);
    if (lane == 0) cbred[w] = cbs;

    // ---- reduce over p with IN-REGISTER wy ----
    // C/D layout: p = 32w+16mi+4qd+reg, l = 16ni+ln (V1-verified).
    // wy(t_p) = (-1)^p sin(64 posy) cos(th)/sin(th), th = posy/2 - p*beta.
    // Seed sincos(posy/2); rotate by -qd*(pi/32) [per-lane exact consts],
    // then -w*(pi/4) [wave-uniform exact consts] -> th at p0 = 32w+4qd.
    const float R2 = 0.7071067811865476f;
    const float CQ = (qd == 0) ? 1.0f : (qd == 1) ? 0.9951847266721969f
                   : (qd == 2) ? 0.9807852804032304f : 0.9569403357322088f;
    const float SQ = (qd == 0) ? 0.0f : (qd == 1) ? 0.0980171403295606f
                   : (qd == 2) ? 0.19509032201612825f : 0.29028467725446233f;
    const float CW = (w == 0) ? 1.0f : (w == 1) ? R2 : (w == 2) ? 0.0f : -R2;
    const float SW = (w == 0) ? 0.0f : (w == 1) ? R2 : (w == 2) ? 1.0f : R2;

    float part[4];
#pragma unroll
    for (int ni = 0; ni < 4; ++ni) {
        const int ly = 16 * ni + ln;
        const float py = posyL[ly];
        const float n0 = s64Y[ly];
        float sy, cy;
        sincosf(0.5f * py, &sy, &cy);
        float s1 = sy * CQ - cy * SQ;
        float c1 = cy * CQ + sy * SQ;
        float s0 = s1 * CW - c1 * SW;
        float c0 = c1 * CW + s1 * SW;
        float ssum = 0.f;
#pragma unroll
        for (int mi = 0; mi < 2; ++mi) {
            float ws_ = s0, wc_ = c0;
            const int pbase = 32 * w + 16 * mi + 4 * qd;
#pragma unroll
            for (int reg = 0; reg < 4; ++reg) {
                const int p = pbase + reg;
                const float num = (reg & 1) ? -n0 : n0;   // (-1)^p, p parity = reg parity
                float wv;
                if (__builtin_expect(fabsf(ws_) >= 2e-3f, 1)) {
                    wv = num * wc_ * __builtin_amdgcn_rcpf(ws_);
                } else {
                    float ta = py - step * (float)p;
                    float nh, nl;
                    if (ta > -1.0f) { nh = ndh[p];  nl = ndl[p]; }
                    else            { nh = ndh2[p]; nl = ndl2[p]; }
                    float u = (py - nh) - nl;
                    if (fabsf(u) < 1e-7f) {
                        wv = 128.0f;
                    } else {
                        float hh = 0.5f * u;
                        float s2 = hh * (1.0f - 0.16666667f * hh * hh);
                        float c2 = 1.0f - 0.5f * hh * hh;
                        wv = num * c2 * __builtin_amdgcn_rcpf(s2);
                    }
                }
                ssum += acc[mi][ni][reg] * wv;
                float ns = ws_ * CB - wc_ * SB;    // rotate by -beta
                wc_ = wc_ * CB + ws_ * SB;
                ws_ = ns;
            }
            if (mi == 0) {                          // advance seed by -16*beta
                float ns = s0 * C16 - c0 * S16;
                c0 = c0 * C16 + s0 * S16;
                s0 = ns;
            }
        }
        ssum += __shfl_xor(ssum, 16, 64);
        ssum += __shfl_xor(ssum, 32, 64);
        part[ni] = ssum;
    }
    if (qd == 0) {
#pragma unroll
        for (int ni = 0; ni < 4; ++ni) partial[w][16 * ni + ln] = part[ni];
    }
    __syncthreads();

    if (tid < TILE_L) {
        float cb = (cbred[0] + cbred[1]) + (cbred[2] + cbred[3]);
        float s = (partial[0][tid] + partial[1][tid]) + (partial[2][tid] + partial[3][tid]);
        s -= s64X[tid] * s64Y[tid] * cb;
        out[(size_t)b * LTOT + l0 + tid] = s * (1.0f / 16384.0f);
    }
}

extern "C" void kernel_launch(void* const* d_in, const int* in_sizes, int n_in,
                              void* d_out, int out_size, void* d_ws, size_t ws_size,
                              hipStream_t stream) {
    const float* x0  = (const float*)d_in[0];
    const float* y0  = (const float*)d_in[1];
    const float* psi = (const float*)d_in[2];
    float* out = (float*)d_out;
    (void)d_ws; (void)ws_size;   // unused: single self-contained kernel

    main_kernel<<<16 * (LTOT / TILE_L), NT, 0, stream>>>(x0, y0, psi, out);
}

// Round 3
// 86.671 us; speedup vs baseline: 1.0453x; 1.0453x over previous
//
#include <hip/hip_runtime.h>
#include <math.h>

#ifndef M_PI
#define M_PI 3.14159265358979323846
#endif

typedef _Float16 half8v __attribute__((ext_vector_type(8)));
typedef float float4v __attribute__((ext_vector_type(4)));

constexpr int KDIM = 128;
constexpr int LTOT = 8192;
constexpr int TILE_L = 64;
constexpr int NT = 256;
constexpr int WSTR = 136;   // LDS row stride in halves (128 + 8 pad)

// ---------------------------------------------------------------------------
// V4 = V3 (passed, absmax 0.015625) with two deltas:
//   (1) __launch_bounds__(256,4): V3's (256,7) forced a ~73-VGPR cap and
//       plausibly spilled in the register-heavy reduce; don't force it.
//   (2) sincos(py/2) precomputed into LDS by the y-stager threads; the reduce
//       loads 2 floats per ni instead of calling sincosf 4x per thread.
// Structure: wyT eliminated from LDS (21.8KB total -> 7 blocks/CU).
//   wx     : Dirichlet weights via rotation recurrence (V1 program, tid<128)
//   tmp    = psi * WX via mfma_f32_16x16x32_f16 (V1 loop, acc[2][4])
//   C_b    = sum (-1)^{p+q} psi from the GEMM's own A loads (V1)
//   wy     : generated in-register in the reduce from LDS sincos seeds via
//            exact-constant rotations (qd*pi/32, w*pi/4) + beta recurrence
//   out[l] = (sum_p wy[p][l]*tmp[p][l] - sin64x*sin64y*C_b) / K^2
// RULE (R4-R7 isolation): never hold A-fragment registers live across the
// unrolled build loop — a_raw is loaded strictly after it.
// ---------------------------------------------------------------------------
__global__ __launch_bounds__(NT, 4) void main_kernel(const float* __restrict__ x0,
        const float* __restrict__ y0, const float* __restrict__ psi,
        float* __restrict__ out) {
    __shared__ _Float16 wxT[TILE_L][WSTR];         // [l][q]
    __shared__ float ndh[KDIM], ndl[KDIM], ndh2[KDIM], ndl2[KDIM];
    __shared__ float s64X[TILE_L];
    __shared__ float posyL[TILE_L];
    __shared__ float s64Y[TILE_L];
    __shared__ float syL[TILE_L];
    __shared__ float cyL[TILE_L];
    __shared__ float partial[4][TILE_L];
    __shared__ float cbred[4];

    const int tid = threadIdx.x;
    const int lane = tid & 63;
    const int w = tid >> 6;
    const int bid = blockIdx.x;
    const int b = bid >> 7;
    const int l0 = (bid & 127) * TILE_L;
    const int qd = lane >> 4;          // quad 0..3
    const int ln = lane & 15;

    const float* Pb = psi + (size_t)b * 16384;

    // ---- node tables for the rare slow path ----
    if (tid < KDIM) {
        double d = (double)tid * (M_PI / 64.0);
        float h = (float)d;
        ndh[tid] = h; ndl[tid] = (float)(d - (double)h);
        double d2 = d - 2.0 * M_PI;
        float h2 = (float)d2;
        ndh2[tid] = h2; ndl2[tid] = (float)(d2 - (double)h2);
    }

    // ---- setup: tid<128 are wx builders (V1 program: l=tid&63, hf=(tid>>6)&1);
    //      tid in [128,192) stage y-tile (posy, sin(64y), sincos(y/2)) ----
    const int l = tid & 63;
    const int hf = (tid >> 6) & 1;
    float pos = 0.f, s64 = 0.f, cs_s = 0.f, cs_c = 0.f;
    if (tid < 128) {
        pos = x0[(size_t)b * LTOT + l0 + l];
        s64 = sinf(64.0f * pos);
        float sa, ca;
        sincosf(0.5f * pos, &sa, &ca);
        if (hf == 0) { cs_s = sa; cs_c = ca; s64X[l] = s64; }
        else         { cs_s = -ca; cs_c = sa; }        // exact rotate by -pi/2
    } else if (tid < 192) {
        const int i = tid - 128;
        float py = y0[(size_t)b * LTOT + l0 + i];
        posyL[i] = py;
        s64Y[i] = sinf(64.0f * py);
        float sy, cy;
        sincosf(0.5f * py, &sy, &cy);
        syL[i] = sy; cyL[i] = cy;
    }
    __syncthreads();

    // ---- build wx: w(t_q) = (-1)^q sin(64 pos) cos(th)/sin(th), th = pos/2 - q*beta
    const float CB  = 0.9996988186962042f,  SB  = 0.024541228522912288f;  // beta = pi/128
    const float C16 = 0.9238795325112867f,  S16 = 0.3826834323650898f;    // 16*beta
    const float step = (float)(M_PI / 64.0);
    if (tid < 128) {
        _Float16* dst = &wxT[l][0];
#pragma unroll
        for (int kk = 0; kk < 4; ++kk) {
            float ws_ = cs_s, wc_ = cs_c;
            const int q0 = 64 * hf + 16 * kk;
#pragma unroll
            for (int h8 = 0; h8 < 2; ++h8) {
                _Float16 buf[8];
#pragma unroll
                for (int j = 0; j < 8; ++j) {
                    const int q = q0 + 8 * h8 + j;
                    const float num = (j & 1) ? -s64 : s64;   // sin(64 t_q) exactly
                    float wv;
                    if (__builtin_expect(fabsf(ws_) >= 2e-3f, 1)) {
                        wv = num * wc_ * __builtin_amdgcn_rcpf(ws_);
                    } else {
                        // near grid node: rebuild u = t_q in two-float, Taylor ratio
                        float ta = pos - step * (float)q;
                        float nh, nl;
                        if (ta > -1.0f) { nh = ndh[q];  nl = ndl[q]; }
                        else            { nh = ndh2[q]; nl = ndl2[q]; }
                        float u = (pos - nh) - nl;
                        if (fabsf(u) < 1e-7f) {
                            wv = 128.0f;
                        } else {
                            float hh = 0.5f * u;
                            float s2 = hh * (1.0f - 0.16666667f * hh * hh);
                            float c2 = 1.0f - 0.5f * hh * hh;
                            wv = num * c2 * __builtin_amdgcn_rcpf(s2);
                        }
                    }
                    buf[j] = (_Float16)wv;
                    float ns = ws_ * CB - wc_ * SB;    // rotate by -beta
                    wc_ = wc_ * CB + ws_ * SB;
                    ws_ = ns;
                }
                *(half8v*)&dst[q0 + 8 * h8] = *(half8v*)buf;
            }
            float ns = cs_s * C16 - cs_c * S16;        // reseed: rotate by -16*beta
            cs_c = cs_c * C16 + cs_s * S16;
            cs_s = ns;
        }
    }
    __syncthreads();

    // ---- A k0 load (fp32, L2/HBM), strictly AFTER the build (V1) ----
    float4v a_raw[2][2];
#pragma unroll
    for (int mi = 0; mi < 2; ++mi) {
        const float* rp = Pb + (32 * w + 16 * mi + ln) * 128 + 8 * qd;
        a_raw[mi][0] = *(const float4v*)(rp);
        a_raw[mi][1] = *(const float4v*)(rp + 4);
    }

    // ---- GEMM + in-flight C_b from the same A values (V1) ----
    float4v acc[2][4];
#pragma unroll
    for (int mi = 0; mi < 2; ++mi)
#pragma unroll
        for (int ni = 0; ni < 4; ++ni) acc[mi][ni] = (float4v){0.f, 0.f, 0.f, 0.f};

    float cbs = 0.0f;
#pragma unroll
    for (int k = 0; k < 4; ++k) {
        half8v af[2];
#pragma unroll
        for (int mi = 0; mi < 2; ++mi) {
#pragma unroll
            for (int j = 0; j < 4; ++j) {
                af[mi][j]     = (_Float16)a_raw[mi][0][j];
                af[mi][4 + j] = (_Float16)a_raw[mi][1][j];
            }
            cbs += (a_raw[mi][0].x - a_raw[mi][0].y) + (a_raw[mi][0].z - a_raw[mi][0].w)
                 + (a_raw[mi][1].x - a_raw[mi][1].y) + (a_raw[mi][1].z - a_raw[mi][1].w);
        }
        if (k < 3) {   // prefetch next k-step (af/cbs already captured the values)
#pragma unroll
            for (int mi = 0; mi < 2; ++mi) {
                const float* rp = Pb + (32 * w + 16 * mi + ln) * 128 + (k + 1) * 32 + 8 * qd;
                a_raw[mi][0] = *(const float4v*)(rp);
                a_raw[mi][1] = *(const float4v*)(rp + 4);
            }
        }
#pragma unroll
        for (int ni = 0; ni < 4; ++ni) {
            half8v bf = *(const half8v*)&wxT[16 * ni + ln][k * 32 + 8 * qd];
#pragma unroll
            for (int mi = 0; mi < 2; ++mi)
                acc[mi][ni] = __builtin_amdgcn_mfma_f32_16x16x32_f16(af[mi], bf, acc[mi][ni], 0, 0, 0);
        }
    }

    // row-parity sign, deterministic wave reduction, one partial per wave (V1)
    if (ln & 1) cbs = -cbs;
#pragma unroll
    for (int off = 1; off < 64; off <<= 1) cbs += __shfl_xor(cbs, off, 64);
    if (lane == 0) cbred[w] = cbs;

    // ---- reduce over p with IN-REGISTER wy (V3, validated) ----
    // C/D layout: p = 32w+16mi+4qd+reg, l = 16ni+ln.
    // wy(t_p) = (-1)^p sin(64 posy) cos(th)/sin(th), th = posy/2 - p*beta.
    // Seed sincos(posy/2) from LDS; rotate by -qd*(pi/32) [per-lane exact],
    // then -w*(pi/4) [wave-uniform exact] -> th at p0 = 32w+4qd.
    const float R2 = 0.7071067811865476f;
    const float CQ = (qd == 0) ? 1.0f : (qd == 1) ? 0.9951847266721969f
                   : (qd == 2) ? 0.9807852804032304f : 0.9569403357322088f;
    const float SQ = (qd == 0) ? 0.0f : (qd == 1) ? 0.0980171403295606f
                   : (qd == 2) ? 0.19509032201612825f : 0.29028467725446233f;
    const float CW = (w == 0) ? 1.0f : (w == 1) ? R2 : (w == 2) ? 0.0f : -R2;
    const float SW = (w == 0) ? 0.0f : (w == 1) ? R2 : (w == 2) ? 1.0f : R2;

    float part[4];
#pragma unroll
    for (int ni = 0; ni < 4; ++ni) {
        const int ly = 16 * ni + ln;
        const float py = posyL[ly];
        const float n0 = s64Y[ly];
        const float sy = syL[ly];
        const float cy = cyL[ly];
        float s1 = sy * CQ - cy * SQ;
        float c1 = cy * CQ + sy * SQ;
        float s0 = s1 * CW - c1 * SW;
        float c0 = c1 * CW + s1 * SW;
        float ssum = 0.f;
#pragma unroll
        for (int mi = 0; mi < 2; ++mi) {
            float ws_ = s0, wc_ = c0;
            const int pbase = 32 * w + 16 * mi + 4 * qd;
#pragma unroll
            for (int reg = 0; reg < 4; ++reg) {
                const int p = pbase + reg;
                const float num = (reg & 1) ? -n0 : n0;   // (-1)^p, p parity = reg parity
                float wv;
                if (__builtin_expect(fabsf(ws_) >= 2e-3f, 1)) {
                    wv = num * wc_ * __builtin_amdgcn_rcpf(ws_);
                } else {
                    float ta = py - step * (float)p;
                    float nh, nl;
                    if (ta > -1.0f) { nh = ndh[p];  nl = ndl[p]; }
                    else            { nh = ndh2[p]; nl = ndl2[p]; }
                    float u = (py - nh) - nl;
                    if (fabsf(u) < 1e-7f) {
                        wv = 128.0f;
                    } else {
                        float hh = 0.5f * u;
                        float s2 = hh * (1.0f - 0.16666667f * hh * hh);
                        float c2 = 1.0f - 0.5f * hh * hh;
                        wv = num * c2 * __builtin_amdgcn_rcpf(s2);
                    }
                }
                ssum += acc[mi][ni][reg] * wv;
                float ns = ws_ * CB - wc_ * SB;    // rotate by -beta
                wc_ = wc_ * CB + ws_ * SB;
                ws_ = ns;
            }
            if (mi == 0) {                          // advance seed by -16*beta
                float ns = s0 * C16 - c0 * S16;
                c0 = c0 * C16 + s0 * S16;
                s0 = ns;
            }
        }
        ssum += __shfl_xor(ssum, 16, 64);
        ssum += __shfl_xor(ssum, 32, 64);
        part[ni] = ssum;
    }
    if (qd == 0) {
#pragma unroll
        for (int ni = 0; ni < 4; ++ni) partial[w][16 * ni + ln] = part[ni];
    }
    __syncthreads();

    if (tid < TILE_L) {
        float cb = (cbred[0] + cbred[1]) + (cbred[2] + cbred[3]);
        float s = (partial[0][tid] + partial[1][tid]) + (partial[2][tid] + partial[3][tid]);
        s -= s64X[tid] * s64Y[tid] * cb;
        out[(size_t)b * LTOT + l0 + tid] = s * (1.0f / 16384.0f);
    }
}

extern "C" void kernel_launch(void* const* d_in, const int* in_sizes, int n_in,
                              void* d_out, int out_size, void* d_ws, size_t ws_size,
                              hipStream_t stream) {
    const float* x0  = (const float*)d_in[0];
    const float* y0  = (const float*)d_in[1];
    const float* psi = (const float*)d_in[2];
    float* out = (float*)d_out;
    (void)d_ws; (void)ws_size;   // unused: single self-contained kernel

    main_kernel<<<16 * (LTOT / TILE_L), NT, 0, stream>>>(x0, y0, psi, out);
}